// Round 1
// 59.427 us; speedup vs baseline: 1.0012x; 1.0012x over previous
//
#include <hip/hip_runtime.h>

// Fused: reshape -> 1x1 mix (w1) -> double-unfold conv (w0) -> reshape -> roll(+1, H)
//
// Math per output (c = 4l + p, h, n), with o = (h-1) mod 56:
//   t4[p,j,n]  = sum_q x[2q+j, o, n] * w1[p,q]            (q in [0,64))
//   out[c,h,n] = sum_{j,k,i} w0[l,j,i,k] * t4[p,j, n+k+i-2]
//                gated on (0 <= n+k-1 < 56) AND (0 <= n+k+i-2 < 56)
//
// Round 4: phase-1 rebuilt. The harness's 268 MB poison fill flushes L2+L3
// every iteration, so x is HBM-cold (~900 cyc). The old 64-deep strided
// scalar gather (7168 load insts/block, 224B rows misaligned to 64B lines)
// serialized several cold-HBM latency exposures. Now all 256 threads stage
// the full x row (128ch x 56) into LDS via aligned float4 (<=8 independent
// 16B loads/thread = ONE latency exposure, full cache-line utilization);
// t4 is then a cheap LDS dot. LDS row stride 64 floats -> phase-2 bank =
// n%32 (2-way free, worst 3-way on 8 banks). w0 register fragments load
// between the barriers to overlap the t4 phase. Conv phase unchanged.

__global__ __launch_bounds__(256) void fused_shift_unfold_kernel(
    const float* __restrict__ x,    // [128,56,56]
    const float* __restrict__ w0,   // [32,2,3,3]
    const float* __restrict__ w1,   // [4,64]
    float* __restrict__ out)        // [128,56,56]
{
    __shared__ float s_x[128 * 64];  // s_x[ch*64 + n] = x[ch, o, n] (stride 64)
    __shared__ float s_t4[2][60];    // s_t4[j][n+2] = t4[p,j,n]; pad 2 each side
    __shared__ float s_w0[576];      // [l][j][i][k]

    const int tid = threadIdx.x;
    const int h   = blockIdx.x;           // output H row
    const int p   = blockIdx.y;           // p = c & 3
    const int o   = h ? h - 1 : 55;       // source H row (roll by +1)

    // ---- phase 1: coalesced staging of the whole x row, all 256 threads ----
    // 128 channels x 14 float4 each; slot space padded to 16/channel so
    // ch = f>>4 (no integer division). All global addrs 16B-aligned:
    // ch*12544 + o*224 + m*16.
    #pragma unroll
    for (int r = 0; r < 8; ++r) {
        const int f  = tid + 256 * r;     // [0, 2048)
        const int ch = f >> 4;
        const int m  = f & 15;
        if (m < 14) {
            const float4 v = *(const float4*)(x + ch * 3136 + o * 56 + m * 4);
            *(float4*)&s_x[ch * 64 + m * 4] = v;
        }
    }
    if (tid < 144)                        // w0: 576 floats = 144 float4
        ((float4*)s_w0)[tid] = ((const float4*)w0)[tid];
    if (tid < 8) {                        // s_t4 pads: [j][0,1,58,59]
        const int j  = tid & 1;
        const int q2 = tid >> 1;          // 0..3
        s_t4[j][q2 < 2 ? q2 : q2 + 56] = 0.f;
    }
    __syncthreads();

    // ---- phase 2a (all threads): hoist w0 fragment while t4 computes ----
    const int l = tid >> 3;               // [0,32)
    const int b = tid & 7;
    float wreg[2][9];                     // wreg[j][i*3+k]
    #pragma unroll
    for (int j = 0; j < 2; ++j)
        #pragma unroll
        for (int t = 0; t < 9; ++t)
            wreg[j][t] = s_w0[l * 18 + j * 9 + t];

    // ---- phase 2b (threads 0..111): t4 from LDS ----
    if (tid < 112) {
        const int j = (tid >= 56);
        const int n = tid - j * 56;
        const float* wp = w1 + p * 64;    // wave-uniform -> s_load
        const float* sp = &s_x[j * 64 + n];  // ch=2q+j -> +q*128
        float a0 = 0.f, a1 = 0.f, a2 = 0.f, a3 = 0.f;
        #pragma unroll
        for (int q = 0; q < 64; q += 4) {
            a0 += wp[q + 0] * sp[(q + 0) * 128];
            a1 += wp[q + 1] * sp[(q + 1) * 128];
            a2 += wp[q + 2] * sp[(q + 2) * 128];
            a3 += wp[q + 3] * sp[(q + 3) * 128];
        }
        s_t4[j][n + 2] = (a0 + a1) + (a2 + a3);
    }
    __syncthreads();

    // ---- phase 3: conv + store: thread = (l, b); outputs n = b + 8i ----
    float* obase = out + (l * 4 + p) * 3136 + h * 56;
    #pragma unroll
    for (int i7 = 0; i7 < 7; ++i7) {
        const int n = b + i7 * 8;         // [0,56)
        float acc = 0.f;
        #pragma unroll
        for (int k = 0; k < 3; ++k) {
            float s = 0.f;
            #pragma unroll
            for (int j = 0; j < 2; ++j) {
                const float* rp = &s_t4[j][n];   // rp[d] = t4[.., n+d-2]
                s += wreg[j][0 + k] * rp[k + 0]; // i=0
                s += wreg[j][3 + k] * rp[k + 1]; // i=1
                s += wreg[j][6 + k] * rp[k + 2]; // i=2
            }
            const int m = n + k - 1;             // first-unfold position
            acc += ((unsigned)m < 56u) ? s : 0.f;
        }
        obase[n] = acc;
    }
}

extern "C" void kernel_launch(void* const* d_in, const int* in_sizes, int n_in,
                              void* d_out, int out_size, void* d_ws, size_t ws_size,
                              hipStream_t stream) {
    (void)in_sizes; (void)n_in; (void)out_size; (void)d_ws; (void)ws_size;
    const float* x  = (const float*)d_in[0];   // [1,128,56,56]
    const float* w0 = (const float*)d_in[1];   // [32,2,3,3]
    const float* w1 = (const float*)d_in[2];   // [4,64]
    float* out = (float*)d_out;                // [1,128,56,56]

    dim3 grid(56, 4);
    fused_shift_unfold_kernel<<<grid, 256, 0, stream>>>(x, w0, w1, out);
}